// Round 1
// baseline (617.005 us; speedup 1.0000x reference)
//
#include <hip/hip_runtime.h>

// CoRACommonEmbedding: out[t] = emb[x[t]] + (lora_B[x[t]] . effA) * SCALING
//   effA[r][d] = lora_A[r][d] * (rank_pattern[r] > 0.1)
// Never materialize the VOCABxD delta: push low-rank product through gather.
//
// Layout: 32 lanes per token, each lane owns one float4 of the D=128 row.
// Each thread keeps its 8x{float4} column slice of effA in registers (loaded
// once, reused across the grid-stride token loop).

constexpr int D = 128;
constexpr int R = 8;
constexpr float SCALING = 2.0f;        // LORA_ALPHA / R = 16 / 8
constexpr float RANK_THRESHOLD = 0.1f;

__global__ __launch_bounds__(256) void cora_embed_kernel(
    const int*   __restrict__ x,            // [N] token ids
    const float* __restrict__ emb,          // [VOCAB, D]
    const float* __restrict__ lora_A,       // [R, D]
    const float* __restrict__ lora_B,       // [VOCAB, R]
    const float* __restrict__ rank_pattern, // [R]
    float*       __restrict__ out,          // [N, D]
    int n_tokens)
{
    const int d4  = threadIdx.x & 31;   // which float4 of the 128-wide row
    const int row = threadIdx.x >> 5;   // token slot within block: 0..7

    // Per-thread column slice of effective_A (masked + pre-scaled).
    // 8 x float4 = 32 VGPRs, loaded once; lora_A is 4 KB so these hit L1/L2.
    float4 A4[R];
#pragma unroll
    for (int r = 0; r < R; ++r) {
        const float g = (rank_pattern[r] > RANK_THRESHOLD) ? SCALING : 0.0f;
        float4 a = reinterpret_cast<const float4*>(lora_A)[r * (D / 4) + d4];
        A4[r].x = a.x * g;
        A4[r].y = a.y * g;
        A4[r].z = a.z * g;
        A4[r].w = a.w * g;
    }

    const int stride = gridDim.x * 8;   // token slots per pass
    for (int t = blockIdx.x * 8 + row; t < n_tokens; t += stride) {
        const int idx = x[t];

        const float4* erow = reinterpret_cast<const float4*>(emb + (size_t)idx * D);
        const float4* brow = reinterpret_cast<const float4*>(lora_B + (size_t)idx * R);

        float4 o  = erow[d4];           // coalesced 512 B row read (32 lanes)
        float4 b0 = brow[0];            // same-address across 32 lanes -> L1 broadcast
        float4 b1 = brow[1];
        const float b[R] = {b0.x, b0.y, b0.z, b0.w, b1.x, b1.y, b1.z, b1.w};

#pragma unroll
        for (int r = 0; r < R; ++r) {
            o.x = fmaf(b[r], A4[r].x, o.x);
            o.y = fmaf(b[r], A4[r].y, o.y);
            o.z = fmaf(b[r], A4[r].z, o.z);
            o.w = fmaf(b[r], A4[r].w, o.w);
        }

        reinterpret_cast<float4*>(out + (size_t)t * D)[d4] = o;  // coalesced 512 B
    }
}

extern "C" void kernel_launch(void* const* d_in, const int* in_sizes, int n_in,
                              void* d_out, int out_size, void* d_ws, size_t ws_size,
                              hipStream_t stream) {
    const int*   x            = (const int*)d_in[0];
    const float* emb          = (const float*)d_in[1];
    const float* lora_A       = (const float*)d_in[2];
    const float* lora_B       = (const float*)d_in[3];
    const float* rank_pattern = (const float*)d_in[4];
    float*       out          = (float*)d_out;

    const int n_tokens = in_sizes[0];   // B * L = 819200

    // 4096 blocks x 256 threads: 8 token-slots/block -> 25 grid-stride passes;
    // amortizes the per-thread effA register load, saturates all 256 CUs.
    const int grid = 4096;
    hipLaunchKernelGGL(cora_embed_kernel, dim3(grid), dim3(256), 0, stream,
                       x, emb, lora_A, lora_B, rank_pattern, out, n_tokens);
}